// Round 10
// baseline (299.038 us; speedup 1.0000x reference)
//
#include <hip/hip_runtime.h>
#include <hip/hip_bf16.h>
#include <stdint.h>

typedef float  f32x4  __attribute__((ext_vector_type(4)));
typedef __bf16 bf16x8 __attribute__((ext_vector_type(8)));

#define DEV static __device__ __forceinline__

// XOR swizzle for LDS tiles with 128B rows: byte ^= ((row&7)<<4), row = byte>>7
DEV uint32_t swz128(uint32_t b){ return b ^ ((b>>3)&0x70u); }

// async global->LDS, 16B per lane; LDS dest = wave-uniform base + lane*16
DEV void gl_lds16(const void* g, void* l) {
  __builtin_amdgcn_global_load_lds(
      (__attribute__((address_space(1))) void*)(g),
      (__attribute__((address_space(3))) void*)(l), 16, 0, 0);
}

DEV f32x4 mfma16(bf16x8 a, bf16x8 b, f32x4 c) {
  return __builtin_amdgcn_mfma_f32_16x16x32_bf16(a, b, c, 0, 0, 0);
}

DEV uint32_t pkbf(float a, float b) {
  union { __hip_bfloat162 v; uint32_t u; } c;
  c.v.x = __float2bfloat16(a);
  c.v.y = __float2bfloat16(b);
  return c.u;
}

// ------- depthwise 3x3 conv + BN, float4-vectorized, XCD-chunked -------------
template<int HOUT, int STRIDE, int PAD>
__global__ __launch_bounds__(256) void dwconv_bn_v4(
    const float* __restrict__ x, const float* __restrict__ wdw,
    const float* __restrict__ gamma, const float* __restrict__ beta,
    const float* __restrict__ mean, const float* __restrict__ var,
    __hip_bfloat16* __restrict__ y)
{
  constexpr int TOTAL4 = 8*HOUT*HOUT*96;
  constexpr int NWG = (TOTAL4 + 255)/256;
  const int wg = blockIdx.x;
  const int xcd = wg & 7, o = wg >> 3;
  constexpr int qq = NWG >> 3, rr = NWG & 7;
  const int swz = (xcd < rr ? xcd*(qq+1) : rr*(qq+1) + (xcd-rr)*qq) + o;
  const int idx = swz*256 + (int)threadIdx.x;
  if (idx >= TOTAL4) return;
  const int c4 = idx % 96;
  int t = idx / 96;
  const int j = t % HOUT; t /= HOUT;
  const int i = t % HOUT; const int b = t / HOUT;

  const float* xb = x + (size_t)b*(56*56*384) + c4*4;
  f32x4 acc = {0.f,0.f,0.f,0.f};
  #pragma unroll
  for (int di=0; di<3; ++di) {
    const int ii = i*STRIDE + di - PAD;
    if ((unsigned)ii < 56u) {
      #pragma unroll
      for (int dj=0; dj<3; ++dj) {
        const int jj = j*STRIDE + dj - PAD;
        if ((unsigned)jj < 56u) {
          f32x4 xv = *(const f32x4*)(xb + ((size_t)ii*56 + jj)*384);
          f32x4 wv = *(const f32x4*)(wdw + (di*3+dj)*384 + c4*4);
          acc += xv*wv;
        }
      }
    }
  }
  f32x4 g  = *(const f32x4*)(gamma + c4*4);
  f32x4 be = *(const f32x4*)(beta  + c4*4);
  f32x4 mu = *(const f32x4*)(mean  + c4*4);
  f32x4 va = *(const f32x4*)(var   + c4*4);
  union { ushort u[4]; uint2 v; } pk;
  #pragma unroll
  for (int k=0;k<4;++k) {
    float sc = g[k]*rsqrtf(va[k]+1e-5f);
    union { __hip_bfloat16 h; ushort s; } cv;
    cv.h = __float2bfloat16((acc[k]-mu[k])*sc + be[k]);
    pk.u[k] = cv.s;
  }
  *(uint2*)((char*)y + (size_t)idx*8) = pk.v;
}

// ---------------- merged weight transposes: w(K,N) fp32 -> wT(N,K) bf16 ------
__global__ __launch_bounds__(256) void transpose_all_kernel(
    const float* __restrict__ wq, const float* __restrict__ wkv,
    const float* __restrict__ wo,
    __hip_bfloat16* __restrict__ wTq, __hip_bfloat16* __restrict__ wTkv,
    __hip_bfloat16* __restrict__ wTo)
{
  int i = blockIdx.x*256 + threadIdx.x;
  if (i < 147456) {                       // 384x384
    int n = i / 384, k = i - n*384;
    wTq[i] = __float2bfloat16(wq[(size_t)k*384 + n]);
  } else if (i < 147456 + 294912) {       // 768x384 (N=768)
    int idx = i - 147456;
    int n = idx / 384, k = idx - n*384;
    wTkv[idx] = __float2bfloat16(wkv[(size_t)k*768 + n]);
  } else if (i < 147456 + 294912 + 147456) {
    int idx = i - 442368;
    int n = idx / 384, k = idx - n*384;
    wTo[idx] = __float2bfloat16(wo[(size_t)k*384 + n]);
  }
}

// ---- barrier-free GEMM: K=384, BN=64 strip staged whole in LDS, A->VGPR ----
// Block: 256 rows x 64 cols. Stage B-strip (64x384, swizzled) once; then each
// wave streams its 64 rows with A b128 loads straight from global. No barriers
// after the initial one. EPI 0: bf16 C. EPI 2: bias + f32 C (final output).
template<int EPI>
__global__ __launch_bounds__(256,3) void gemm_nb(
    const __hip_bfloat16* __restrict__ A, const __hip_bfloat16* __restrict__ Bt,
    __hip_bfloat16* __restrict__ C, float* __restrict__ Cf, int M, int N,
    const float* __restrict__ bias)
{
  __shared__ __align__(1024) char Bs[64*768];   // 48KB
  const int t = threadIdx.x, lane = t&63, w = t>>6;
  const int n0 = blockIdx.x*64, m0 = blockIdx.y*256;

  // stage B strip: 3072 x 16B chunks; LDS[row][cib] = B[row][cib ^ (row&7)]
  #pragma unroll
  for (int it=0; it<12; ++it) {
    int ch = it*256 + t;
    int row = ch / 48, cib = ch - row*48;
    const char* src = (const char*)Bt + (size_t)(n0+row)*768 + ((cib ^ (row&7))*16);
    gl_lds16(src, Bs + (size_t)ch*16);
  }
  asm volatile("s_waitcnt vmcnt(0)" ::: "memory");
  __syncthreads();

  // wave w: rows m0 + w*64 .. +63 (4 sub-tiles of 16)
  const char* arow = (const char*)A + (size_t)(m0 + w*64 + (lane&15))*768 + (lane>>4)*16;
  f32x4 acc[4][4];
  #pragma unroll
  for (int mt=0;mt<4;++mt)
    #pragma unroll
    for (int nf=0;nf<4;++nf)
      acc[mt][nf] = f32x4{0.f,0.f,0.f,0.f};

  bf16x8 a[4], an[4];
  #pragma unroll
  for (int mt=0;mt<4;++mt) a[mt] = *(const bf16x8*)(arow + mt*12288);

  #pragma unroll
  for (int kb=0; kb<12; ++kb) {
    if (kb < 11) {
      #pragma unroll
      for (int mt=0;mt<4;++mt)
        an[mt] = *(const bf16x8*)(arow + mt*12288 + (kb+1)*64);
    }
    bf16x8 bfr[4];
    #pragma unroll
    for (int nf=0;nf<4;++nf) {
      uint32_t r = (uint32_t)(nf*16 + (lane&15));
      bfr[nf] = *(const bf16x8*)(Bs + r*768 + (((uint32_t)(kb*64) + (uint32_t)((lane>>4)*16)) ^ ((r&7)<<4)));
    }
    #pragma unroll
    for (int mt=0;mt<4;++mt)
      #pragma unroll
      for (int nf=0;nf<4;++nf)
        acc[mt][nf] = mfma16(a[mt], bfr[nf], acc[mt][nf]);
    #pragma unroll
    for (int mt=0;mt<4;++mt) a[mt] = an[mt];
  }

  float bv[4];
  if (EPI==2) {
    #pragma unroll
    for (int nf=0;nf<4;++nf) bv[nf] = bias[n0 + nf*16 + (lane&15)];
  }
  #pragma unroll
  for (int mt=0;mt<4;++mt) {
    #pragma unroll
    for (int nf=0;nf<4;++nf) {
      #pragma unroll
      for (int i=0;i<4;++i) {
        int row = m0 + w*64 + mt*16 + (lane>>4)*4 + i;
        int col = n0 + nf*16 + (lane&15);
        if (EPI==2) Cf[(size_t)row*N + col] = acc[mt][nf][i] + bv[nf];
        else        C[(size_t)row*N + col] = __float2bfloat16(acc[mt][nf][i]);
      }
    }
  }
}

// ---------------- 128x128x(K) bf16 GEMM (kv path, EPI1 vT scatter) -----------
template<int EPI>
__global__ __launch_bounds__(256,2) void gemm128_kernel(
    const __hip_bfloat16* __restrict__ A, const __hip_bfloat16* __restrict__ Bt,
    __hip_bfloat16* __restrict__ C, float* __restrict__ Cf, int M, int N, int K,
    const float* __restrict__ bias, __hip_bfloat16* __restrict__ vT)
{
  __shared__ __align__(1024) char As[128*64*2];
  __shared__ __align__(1024) char Bs[128*64*2];
  const int t = threadIdx.x;
  const int lane = t & 63;
  const int wave = t >> 6;
  const int wr = wave >> 1, wc = wave & 1;
  const int m0 = blockIdx.y*128, n0 = blockIdx.x*128;
  const int ldab = K*2;

  const char* aS[4]; const char* bS[4];
  #pragma unroll
  for (int j=0;j<4;++j) {
    uint32_t d = (uint32_t)(j*256 + t)*16u;
    uint32_t l = swz128(d);
    uint32_t r = l >> 7, cb = l & 127u;
    aS[j] = (const char*)A  + (size_t)(m0+(int)r)*ldab + cb;
    bS[j] = (const char*)Bt + (size_t)(n0+(int)r)*ldab + cb;
  }
  f32x4 acc[4][4];
  #pragma unroll
  for (int m=0;m<4;++m)
    #pragma unroll
    for (int n=0;n<4;++n)
      acc[m][n] = f32x4{0.f,0.f,0.f,0.f};

  const uint32_t kbOff = (uint32_t)((lane>>4)*16);
  const uint32_t arow = (uint32_t)(wr*64 + (lane&15));
  const uint32_t brow = (uint32_t)(wc*64 + (lane&15));

  const int nk = K >> 6;
  for (int kt=0; kt<nk; ++kt) {
    #pragma unroll
    for (int j=0;j<4;++j) {
      uint32_t d = (uint32_t)(j*256+t)*16u;
      gl_lds16(aS[j] + (size_t)kt*128, As + d);
      gl_lds16(bS[j] + (size_t)kt*128, Bs + d);
    }
    __syncthreads();
    #pragma unroll
    for (int ks=0;ks<2;++ks) {
      bf16x8 af[4], bf[4];
      #pragma unroll
      for (int m=0;m<4;++m)
        af[m] = *(const bf16x8*)(As + swz128((arow + m*16)*128 + ks*64 + kbOff));
      #pragma unroll
      for (int n=0;n<4;++n)
        bf[n] = *(const bf16x8*)(Bs + swz128((brow + n*16)*128 + ks*64 + kbOff));
      #pragma unroll
      for (int m=0;m<4;++m)
        #pragma unroll
        for (int n=0;n<4;++n)
          acc[m][n] = mfma16(af[m], bf[n], acc[m][n]);
    }
    __syncthreads();
  }
  #pragma unroll
  for (int m=0;m<4;++m) {
    #pragma unroll
    for (int n=0;n<4;++n) {
      #pragma unroll
      for (int i=0;i<4;++i) {
        int row = m0 + wr*64 + m*16 + (lane>>4)*4 + i;
        int col = n0 + wc*64 + n*16 + (lane&15);
        float v = acc[m][n][i];
        if (EPI==2) {
          Cf[(size_t)row*N + col] = v + bias[col];
        } else {
          C[(size_t)row*N + col] = __float2bfloat16(v);
          if (EPI==1 && col >= 384) {
            int bb = row / 784;
            int p  = row - bb*784;
            int cc = col - 384;
            int hh = cc >> 6, dd = cc & 63;
            vT[(size_t)((bb*6+hh)*64+dd)*784 + p] = __float2bfloat16(v);
          }
        }
      }
    }
  }
}

// ---------------- flash attention v3.1: zero-hoist + no tile-13 prefetch ----
__global__ __launch_bounds__(256,4) void attn_kernel(
    const __hip_bfloat16* __restrict__ qb, const __hip_bfloat16* __restrict__ kvb,
    const __hip_bfloat16* __restrict__ vTb, __hip_bfloat16* __restrict__ ob)
{
  __shared__ __align__(1024) char Ks[2*8192];   // [buf][64 kv x 64 d] swz128
  __shared__ __align__(1024) char Vs[2*8192];   // [buf][64 d x 64 kv] swz128
  __shared__ __align__(1024) char Ps[4*2048];   // per-wave [16 q x 64 kv] swz128
  const int t = threadIdx.x, lane = t&63, w = t>>6;
  const int bh = blockIdx.y;
  const int b = bh / 6, h = bh - b*6;
  const int qp0 = blockIdx.x * 64;

  const float K1 = 0.18033688011112042f;   // 0.125 * log2(e)
  const float C2 = 5.770780163555851f;     // 4.0  * log2(e)

  const char* qrow = (const char*)qb
      + ((size_t)(b*3136 + qp0 + w*16 + (lane&15))*384 + h*64)*2 + (lane>>4)*16;
  bf16x8 aq[2];
  aq[0] = *(const bf16x8*)(qrow);
  aq[1] = *(const bf16x8*)(qrow + 64);

  const char* kbase = (const char*)kvb + ((size_t)(b*784)*768 + h*64)*2;  // row 1536B
  const char* vbase = (const char*)vTb + (size_t)((b*6+h)*64)*1568;       // row 1568B

  const uint32_t d0 = (uint32_t)t*16u, d1 = (uint32_t)(256+t)*16u;
  const uint32_t l0 = swz128(d0), l1 = swz128(d1);
  const int      kr0 = (int)(l0>>7), kr1 = (int)(l1>>7);
  const uint32_t c0 = l0&127u, c1 = l1&127u;

  #define STAGE(buf, kv0) do {                                               \
    int a0 = (kv0)+kr0; if (a0>783) a0=783;                                  \
    int a1 = (kv0)+kr1; if (a1>783) a1=783;                                  \
    gl_lds16(kbase + (size_t)a0*1536 + c0, Ks + (buf)*8192 + d0);            \
    gl_lds16(kbase + (size_t)a1*1536 + c1, Ks + (buf)*8192 + d1);            \
    gl_lds16(vbase + (size_t)kr0*1568 + (size_t)(kv0)*2 + c0, Vs + (buf)*8192 + d0); \
    gl_lds16(vbase + (size_t)kr1*1568 + (size_t)(kv0)*2 + c1, Vs + (buf)*8192 + d1); \
  } while(0)

  STAGE(0, 0);
  asm volatile("s_waitcnt vmcnt(0)" ::: "memory");
  __syncthreads();

  float l_part = 0.f;
  f32x4 o[4];
  #pragma unroll
  for (int nf=0;nf<4;++nf) o[nf] = f32x4{0.f,0.f,0.f,0.f};
  f32x4 z = {0.f,0.f,0.f,0.f};
  asm volatile("" : "+v"(z));   // pin zero C-operand in regs (kills per-iter init)

  char* Pb = Ps + w*2048;
  const uint32_t fragOff = (uint32_t)((lane>>4)*16);
  const uint32_t pwBase = (uint32_t)(lane&15)*128 + (uint32_t)((lane>>4)*4)*2;

  for (int kt=0; kt<13; ++kt) {
    const int cur = kt & 1;
    if (kt < 12) STAGE(cur^1, (kt+1)*64);
    const char* Kb = Ks + cur*8192;
    const char* Vb = Vs + cur*8192;

    // S^T = (K Q^T): s[nf][i] = S[kv=nf*16+(lane>>4)*4+i][q=lane&15]
    f32x4 s[4];
    #pragma unroll
    for (int nf=0;nf<4;++nf) {
      bf16x8 kf0 = *(const bf16x8*)(Kb + swz128((uint32_t)(nf*16+(lane&15))*128 + fragOff));
      s[nf] = mfma16(kf0, aq[0], z);
      bf16x8 kf1 = *(const bf16x8*)(Kb + swz128((uint32_t)(nf*16+(lane&15))*128 + 64 + fragOff));
      s[nf] = mfma16(kf1, aq[1], s[nf]);
    }

    // P = 2^(S*K1 - C2); tail tile: only frag nf=0 valid (kv 768..783)
    #pragma unroll
    for (int nf=0;nf<4;++nf) {
      uint64_t pk;
      if (kt == 12 && nf > 0) {
        pk = 0ull;
      } else {
        float p0 = exp2f(fmaf(s[nf][0], K1, -C2));
        float p1 = exp2f(fmaf(s[nf][1], K1, -C2));
        float p2 = exp2f(fmaf(s[nf][2], K1, -C2));
        float p3 = exp2f(fmaf(s[nf][3], K1, -C2));
        l_part += (p0+p1) + (p2+p3);
        pk = (uint64_t)pkbf(p2,p3) << 32 | pkbf(p0,p1);
      }
      *(uint64_t*)(Pb + swz128(pwBase + nf*32)) = pk;
    }

    // O += P V
    #pragma unroll
    for (int ks=0;ks<2;++ks) {
      bf16x8 pa = *(const bf16x8*)(Pb + swz128((uint32_t)(lane&15)*128 + ks*64 + fragOff));
      #pragma unroll
      for (int nf=0;nf<4;++nf) {
        bf16x8 vf = *(const bf16x8*)(Vb + swz128((uint32_t)(nf*16+(lane&15))*128 + ks*64 + fragOff));
        o[nf] = mfma16(pa, vf, o[nf]);
      }
    }

    asm volatile("s_waitcnt vmcnt(0)" ::: "memory");
    __syncthreads();
  }
  #undef STAGE

  l_part += __shfl_xor(l_part, 16);
  l_part += __shfl_xor(l_part, 32);

  char* obase = (char*)ob + ((size_t)(b*3136 + qp0 + w*16 + (lane>>4)*4)*384 + h*64 + (lane&15))*2;
  #pragma unroll
  for (int i=0;i<4;++i) {
    float li = __shfl(l_part, (lane>>4)*4 + i);
    float inv = 1.0f / li;
    #pragma unroll
    for (int nf=0;nf<4;++nf)
      *(__hip_bfloat16*)(obase + (size_t)i*768 + nf*32) = __float2bfloat16(o[nf][i]*inv);
  }
}

// ---------------- launch --------------------------------------------------
extern "C" void kernel_launch(void* const* d_in, const int* in_sizes, int n_in,
                              void* d_out, int out_size, void* d_ws, size_t ws_size,
                              hipStream_t stream)
{
  const float* x      = (const float*)d_in[0];
  const float* wdwq   = (const float*)d_in[1];
  const float* gq     = (const float*)d_in[2];
  const float* bq     = (const float*)d_in[3];
  const float* mq     = (const float*)d_in[4];
  const float* vq     = (const float*)d_in[5];
  const float* wpwq   = (const float*)d_in[6];
  const float* wdwkv  = (const float*)d_in[7];
  const float* gkv    = (const float*)d_in[8];
  const float* bkv    = (const float*)d_in[9];
  const float* mkv    = (const float*)d_in[10];
  const float* vkv    = (const float*)d_in[11];
  const float* wpwkv  = (const float*)d_in[12];
  const float* wout   = (const float*)d_in[13];
  const float* bout   = (const float*)d_in[14];

  char* ws = (char*)d_ws;
  __hip_bfloat16* yq    = (__hip_bfloat16*)(ws + 0);          // 25088x384 (reused as o)
  __hip_bfloat16* qbuf  = (__hip_bfloat16*)(ws + 19267584);   // 25088x384
  __hip_bfloat16* ykv   = (__hip_bfloat16*)(ws + 38535168);   // 6272x384
  __hip_bfloat16* kvbuf = (__hip_bfloat16*)(ws + 43352064);   // 6272x768
  __hip_bfloat16* vT    = (__hip_bfloat16*)(ws + 52985856);   // 48x64x784 (+64K slack)
  __hip_bfloat16* wTq   = (__hip_bfloat16*)(ws + 57868288);   // 384x384
  __hip_bfloat16* wTkv  = (__hip_bfloat16*)(ws + 58163200);   // 768x384
  __hip_bfloat16* wTo   = (__hip_bfloat16*)(ws + 58753024);   // 384x384

  dwconv_bn_v4<56,1,1><<<dim3(9408),256,0,stream>>>(x,wdwq,gq,bq,mq,vq,yq);
  dwconv_bn_v4<28,2,0><<<dim3(2352),256,0,stream>>>(x,wdwkv,gkv,bkv,mkv,vkv,ykv);
  transpose_all_kernel<<<dim3(2304),256,0,stream>>>(wpwq, wpwkv, wout, wTq, wTkv, wTo);
  gemm_nb<0><<<dim3(6,98),256,0,stream>>>(yq, wTq, qbuf, nullptr, 25088,384, nullptr);
  gemm128_kernel<1><<<dim3(6,49),256,0,stream>>>(ykv, wTkv, kvbuf, nullptr, 6272,768,384, nullptr, vT);
  attn_kernel<<<dim3(49,48),256,0,stream>>>(qbuf, kvbuf, vT, yq);
  gemm_nb<2><<<dim3(6,98),256,0,stream>>>(yq, wTo, nullptr, (float*)d_out, 25088,384, bout);
}

// Round 11
// 284.793 us; speedup vs baseline: 1.0500x; 1.0500x over previous
//
#include <hip/hip_runtime.h>
#include <hip/hip_bf16.h>
#include <stdint.h>

typedef float  f32x4  __attribute__((ext_vector_type(4)));
typedef __bf16 bf16x8 __attribute__((ext_vector_type(8)));

#define DEV static __device__ __forceinline__

// XOR swizzle for LDS tiles with 128B rows: byte ^= ((row&7)<<4), row = byte>>7
DEV uint32_t swz128(uint32_t b){ return b ^ ((b>>3)&0x70u); }

// async global->LDS, 16B per lane; LDS dest = wave-uniform base + lane*16
DEV void gl_lds16(const void* g, void* l) {
  __builtin_amdgcn_global_load_lds(
      (__attribute__((address_space(1))) void*)(g),
      (__attribute__((address_space(3))) void*)(l), 16, 0, 0);
}

DEV f32x4 mfma16(bf16x8 a, bf16x8 b, f32x4 c) {
  return __builtin_amdgcn_mfma_f32_16x16x32_bf16(a, b, c, 0, 0, 0);
}

DEV uint32_t pkbf(float a, float b) {
  union { __hip_bfloat162 v; uint32_t u; } c;
  c.v.x = __float2bfloat16(a);
  c.v.y = __float2bfloat16(b);
  return c.u;
}

// ------- depthwise 3x3 conv + BN, float4-vectorized, XCD-chunked -------------
template<int HOUT, int STRIDE, int PAD>
__global__ __launch_bounds__(256) void dwconv_bn_v4(
    const float* __restrict__ x, const float* __restrict__ wdw,
    const float* __restrict__ gamma, const float* __restrict__ beta,
    const float* __restrict__ mean, const float* __restrict__ var,
    __hip_bfloat16* __restrict__ y)
{
  constexpr int TOTAL4 = 8*HOUT*HOUT*96;
  constexpr int NWG = (TOTAL4 + 255)/256;
  const int wg = blockIdx.x;
  const int xcd = wg & 7, o = wg >> 3;
  constexpr int qq = NWG >> 3, rr = NWG & 7;
  const int swz = (xcd < rr ? xcd*(qq+1) : rr*(qq+1) + (xcd-rr)*qq) + o;
  const int idx = swz*256 + (int)threadIdx.x;
  if (idx >= TOTAL4) return;
  const int c4 = idx % 96;
  int t = idx / 96;
  const int j = t % HOUT; t /= HOUT;
  const int i = t % HOUT; const int b = t / HOUT;

  const float* xb = x + (size_t)b*(56*56*384) + c4*4;
  f32x4 acc = {0.f,0.f,0.f,0.f};
  #pragma unroll
  for (int di=0; di<3; ++di) {
    const int ii = i*STRIDE + di - PAD;
    if ((unsigned)ii < 56u) {
      #pragma unroll
      for (int dj=0; dj<3; ++dj) {
        const int jj = j*STRIDE + dj - PAD;
        if ((unsigned)jj < 56u) {
          f32x4 xv = *(const f32x4*)(xb + ((size_t)ii*56 + jj)*384);
          f32x4 wv = *(const f32x4*)(wdw + (di*3+dj)*384 + c4*4);
          acc += xv*wv;
        }
      }
    }
  }
  f32x4 g  = *(const f32x4*)(gamma + c4*4);
  f32x4 be = *(const f32x4*)(beta  + c4*4);
  f32x4 mu = *(const f32x4*)(mean  + c4*4);
  f32x4 va = *(const f32x4*)(var   + c4*4);
  union { ushort u[4]; uint2 v; } pk;
  #pragma unroll
  for (int k=0;k<4;++k) {
    float sc = g[k]*rsqrtf(va[k]+1e-5f);
    union { __hip_bfloat16 h; ushort s; } cv;
    cv.h = __float2bfloat16((acc[k]-mu[k])*sc + be[k]);
    pk.u[k] = cv.s;
  }
  *(uint2*)((char*)y + (size_t)idx*8) = pk.v;
}

// ---------------- merged weight transposes: w(K,N) fp32 -> wT(N,K) bf16 ------
__global__ __launch_bounds__(256) void transpose_all_kernel(
    const float* __restrict__ wq, const float* __restrict__ wkv,
    const float* __restrict__ wo,
    __hip_bfloat16* __restrict__ wTq, __hip_bfloat16* __restrict__ wTkv,
    __hip_bfloat16* __restrict__ wTo)
{
  int i = blockIdx.x*256 + threadIdx.x;
  if (i < 147456) {                       // 384x384
    int n = i / 384, k = i - n*384;
    wTq[i] = __float2bfloat16(wq[(size_t)k*384 + n]);
  } else if (i < 147456 + 294912) {       // 768x384 (N=768)
    int idx = i - 147456;
    int n = idx / 384, k = idx - n*384;
    wTkv[idx] = __float2bfloat16(wkv[(size_t)k*768 + n]);
  } else if (i < 147456 + 294912 + 147456) {
    int idx = i - 442368;
    int n = idx / 384, k = idx - n*384;
    wTo[idx] = __float2bfloat16(wo[(size_t)k*384 + n]);
  }
}

// ------- 128x128x(K) bf16 GEMM, DOUBLE-BUFFERED 2-phase, Bt=B^T(N,K) ---------
// Per iter: issue STAGE(t+1) into buf^1 BEFORE computing buf -> load latency
// hides under MFMA+ds_read. LDS 64KB -> 2 blocks/CU.
// EPI 0: bf16 C. EPI 1: + v-half transposed scatter. EPI 2: bias + f32 C.
template<int EPI>
__global__ __launch_bounds__(256,2) void gemm128_kernel(
    const __hip_bfloat16* __restrict__ A, const __hip_bfloat16* __restrict__ Bt,
    __hip_bfloat16* __restrict__ C, float* __restrict__ Cf, int M, int N, int K,
    const float* __restrict__ bias, __hip_bfloat16* __restrict__ vT)
{
  __shared__ __align__(1024) char As[2*16384];
  __shared__ __align__(1024) char Bs[2*16384];
  const int t = threadIdx.x;
  const int lane = t & 63;
  const int wave = t >> 6;
  const int wr = wave >> 1, wc = wave & 1;
  const int m0 = blockIdx.y*128, n0 = blockIdx.x*128;
  const int ldab = K*2;

  const char* aS[4]; const char* bS[4];
  uint32_t dd[4];
  #pragma unroll
  for (int j=0;j<4;++j) {
    uint32_t d = (uint32_t)(j*256 + t)*16u;
    dd[j] = d;
    uint32_t l = swz128(d);
    uint32_t r = l >> 7, cb = l & 127u;
    aS[j] = (const char*)A  + (size_t)(m0+(int)r)*ldab + cb;
    bS[j] = (const char*)Bt + (size_t)(n0+(int)r)*ldab + cb;
  }
  f32x4 acc[4][4];
  #pragma unroll
  for (int m=0;m<4;++m)
    #pragma unroll
    for (int n=0;n<4;++n)
      acc[m][n] = f32x4{0.f,0.f,0.f,0.f};

  const uint32_t kbOff = (uint32_t)((lane>>4)*16);
  const uint32_t arow = (uint32_t)(wr*64 + (lane&15));
  const uint32_t brow = (uint32_t)(wc*64 + (lane&15));

  const int nk = K >> 6;
  // prologue: stage tile 0 into buf 0
  #pragma unroll
  for (int j=0;j<4;++j) {
    gl_lds16(aS[j], As + dd[j]);
    gl_lds16(bS[j], Bs + dd[j]);
  }
  asm volatile("s_waitcnt vmcnt(0)" ::: "memory");
  __syncthreads();

  for (int kt=0; kt<nk; ++kt) {
    const int cur = kt & 1;
    if (kt+1 < nk) {                     // prefetch next tile into other buffer
      #pragma unroll
      for (int j=0;j<4;++j) {
        gl_lds16(aS[j] + (size_t)(kt+1)*128, As + (cur^1)*16384 + dd[j]);
        gl_lds16(bS[j] + (size_t)(kt+1)*128, Bs + (cur^1)*16384 + dd[j]);
      }
    }
    const char* Ab = As + cur*16384;
    const char* Bb = Bs + cur*16384;
    #pragma unroll
    for (int ks=0;ks<2;++ks) {
      bf16x8 af[4], bf[4];
      #pragma unroll
      for (int m=0;m<4;++m)
        af[m] = *(const bf16x8*)(Ab + swz128((arow + m*16)*128 + ks*64 + kbOff));
      #pragma unroll
      for (int n=0;n<4;++n)
        bf[n] = *(const bf16x8*)(Bb + swz128((brow + n*16)*128 + ks*64 + kbOff));
      #pragma unroll
      for (int m=0;m<4;++m)
        #pragma unroll
        for (int n=0;n<4;++n)
          acc[m][n] = mfma16(af[m], bf[n], acc[m][n]);
    }
    asm volatile("s_waitcnt vmcnt(0)" ::: "memory");  // next tile landed
    __syncthreads();                                   // all waves done w/ cur
  }
  #pragma unroll
  for (int m=0;m<4;++m) {
    #pragma unroll
    for (int n=0;n<4;++n) {
      #pragma unroll
      for (int i=0;i<4;++i) {
        int row = m0 + wr*64 + m*16 + (lane>>4)*4 + i;
        int col = n0 + wc*64 + n*16 + (lane&15);
        float v = acc[m][n][i];
        if (EPI==2) {
          Cf[(size_t)row*N + col] = v + bias[col];
        } else {
          C[(size_t)row*N + col] = __float2bfloat16(v);
          if (EPI==1 && col >= 384) {
            int bb = row / 784;
            int p  = row - bb*784;
            int cc = col - 384;
            int hh = cc >> 6, dd2 = cc & 63;
            vT[(size_t)((bb*6+hh)*64+dd2)*784 + p] = __float2bfloat16(v);
          }
        }
      }
    }
  }
}

// ---------------- flash attention v3.1: zero-hoist + no tile-13 prefetch ----
__global__ __launch_bounds__(256,4) void attn_kernel(
    const __hip_bfloat16* __restrict__ qb, const __hip_bfloat16* __restrict__ kvb,
    const __hip_bfloat16* __restrict__ vTb, __hip_bfloat16* __restrict__ ob)
{
  __shared__ __align__(1024) char Ks[2*8192];   // [buf][64 kv x 64 d] swz128
  __shared__ __align__(1024) char Vs[2*8192];   // [buf][64 d x 64 kv] swz128
  __shared__ __align__(1024) char Ps[4*2048];   // per-wave [16 q x 64 kv] swz128
  const int t = threadIdx.x, lane = t&63, w = t>>6;
  const int bh = blockIdx.y;
  const int b = bh / 6, h = bh - b*6;
  const int qp0 = blockIdx.x * 64;

  const float K1 = 0.18033688011112042f;   // 0.125 * log2(e)
  const float C2 = 5.770780163555851f;     // 4.0  * log2(e)

  const char* qrow = (const char*)qb
      + ((size_t)(b*3136 + qp0 + w*16 + (lane&15))*384 + h*64)*2 + (lane>>4)*16;
  bf16x8 aq[2];
  aq[0] = *(const bf16x8*)(qrow);
  aq[1] = *(const bf16x8*)(qrow + 64);

  const char* kbase = (const char*)kvb + ((size_t)(b*784)*768 + h*64)*2;  // row 1536B
  const char* vbase = (const char*)vTb + (size_t)((b*6+h)*64)*1568;       // row 1568B

  const uint32_t d0 = (uint32_t)t*16u, d1 = (uint32_t)(256+t)*16u;
  const uint32_t l0 = swz128(d0), l1 = swz128(d1);
  const int      kr0 = (int)(l0>>7), kr1 = (int)(l1>>7);
  const uint32_t c0 = l0&127u, c1 = l1&127u;

  #define STAGE(buf, kv0) do {                                               \
    int a0 = (kv0)+kr0; if (a0>783) a0=783;                                  \
    int a1 = (kv0)+kr1; if (a1>783) a1=783;                                  \
    gl_lds16(kbase + (size_t)a0*1536 + c0, Ks + (buf)*8192 + d0);            \
    gl_lds16(kbase + (size_t)a1*1536 + c1, Ks + (buf)*8192 + d1);            \
    gl_lds16(vbase + (size_t)kr0*1568 + (size_t)(kv0)*2 + c0, Vs + (buf)*8192 + d0); \
    gl_lds16(vbase + (size_t)kr1*1568 + (size_t)(kv0)*2 + c1, Vs + (buf)*8192 + d1); \
  } while(0)

  STAGE(0, 0);
  asm volatile("s_waitcnt vmcnt(0)" ::: "memory");
  __syncthreads();

  float l_part = 0.f;
  f32x4 o[4];
  #pragma unroll
  for (int nf=0;nf<4;++nf) o[nf] = f32x4{0.f,0.f,0.f,0.f};
  f32x4 z = {0.f,0.f,0.f,0.f};
  asm volatile("" : "+v"(z));   // pin zero C-operand in regs (kills per-iter init)

  char* Pb = Ps + w*2048;
  const uint32_t fragOff = (uint32_t)((lane>>4)*16);
  const uint32_t pwBase = (uint32_t)(lane&15)*128 + (uint32_t)((lane>>4)*4)*2;

  for (int kt=0; kt<13; ++kt) {
    const int cur = kt & 1;
    if (kt < 12) STAGE(cur^1, (kt+1)*64);
    const char* Kb = Ks + cur*8192;
    const char* Vb = Vs + cur*8192;

    // S^T = (K Q^T): s[nf][i] = S[kv=nf*16+(lane>>4)*4+i][q=lane&15]
    f32x4 s[4];
    #pragma unroll
    for (int nf=0;nf<4;++nf) {
      bf16x8 kf0 = *(const bf16x8*)(Kb + swz128((uint32_t)(nf*16+(lane&15))*128 + fragOff));
      s[nf] = mfma16(kf0, aq[0], z);
      bf16x8 kf1 = *(const bf16x8*)(Kb + swz128((uint32_t)(nf*16+(lane&15))*128 + 64 + fragOff));
      s[nf] = mfma16(kf1, aq[1], s[nf]);
    }

    // P = 2^(S*K1 - C2); tail tile: only frag nf=0 valid (kv 768..783)
    #pragma unroll
    for (int nf=0;nf<4;++nf) {
      uint64_t pk;
      if (kt == 12 && nf > 0) {
        pk = 0ull;
      } else {
        float p0 = exp2f(fmaf(s[nf][0], K1, -C2));
        float p1 = exp2f(fmaf(s[nf][1], K1, -C2));
        float p2 = exp2f(fmaf(s[nf][2], K1, -C2));
        float p3 = exp2f(fmaf(s[nf][3], K1, -C2));
        l_part += (p0+p1) + (p2+p3);
        pk = (uint64_t)pkbf(p2,p3) << 32 | pkbf(p0,p1);
      }
      *(uint64_t*)(Pb + swz128(pwBase + nf*32)) = pk;
    }

    // O += P V
    #pragma unroll
    for (int ks=0;ks<2;++ks) {
      bf16x8 pa = *(const bf16x8*)(Pb + swz128((uint32_t)(lane&15)*128 + ks*64 + fragOff));
      #pragma unroll
      for (int nf=0;nf<4;++nf) {
        bf16x8 vf = *(const bf16x8*)(Vb + swz128((uint32_t)(nf*16+(lane&15))*128 + ks*64 + fragOff));
        o[nf] = mfma16(pa, vf, o[nf]);
      }
    }

    asm volatile("s_waitcnt vmcnt(0)" ::: "memory");
    __syncthreads();
  }
  #undef STAGE

  l_part += __shfl_xor(l_part, 16);
  l_part += __shfl_xor(l_part, 32);

  char* obase = (char*)ob + ((size_t)(b*3136 + qp0 + w*16 + (lane>>4)*4)*384 + h*64 + (lane&15))*2;
  #pragma unroll
  for (int i=0;i<4;++i) {
    float li = __shfl(l_part, (lane>>4)*4 + i);
    float inv = 1.0f / li;
    #pragma unroll
    for (int nf=0;nf<4;++nf)
      *(__hip_bfloat16*)(obase + (size_t)i*768 + nf*32) = __float2bfloat16(o[nf][i]*inv);
  }
}

// ---------------- launch --------------------------------------------------
extern "C" void kernel_launch(void* const* d_in, const int* in_sizes, int n_in,
                              void* d_out, int out_size, void* d_ws, size_t ws_size,
                              hipStream_t stream)
{
  const float* x      = (const float*)d_in[0];
  const float* wdwq   = (const float*)d_in[1];
  const float* gq     = (const float*)d_in[2];
  const float* bq     = (const float*)d_in[3];
  const float* mq     = (const float*)d_in[4];
  const float* vq     = (const float*)d_in[5];
  const float* wpwq   = (const float*)d_in[6];
  const float* wdwkv  = (const float*)d_in[7];
  const float* gkv    = (const float*)d_in[8];
  const float* bkv    = (const float*)d_in[9];
  const float* mkv    = (const float*)d_in[10];
  const float* vkv    = (const float*)d_in[11];
  const float* wpwkv  = (const float*)d_in[12];
  const float* wout   = (const float*)d_in[13];
  const float* bout   = (const float*)d_in[14];

  char* ws = (char*)d_ws;
  __hip_bfloat16* yq    = (__hip_bfloat16*)(ws + 0);          // 25088x384 (reused as o)
  __hip_bfloat16* qbuf  = (__hip_bfloat16*)(ws + 19267584);   // 25088x384
  __hip_bfloat16* ykv   = (__hip_bfloat16*)(ws + 38535168);   // 6272x384
  __hip_bfloat16* kvbuf = (__hip_bfloat16*)(ws + 43352064);   // 6272x768
  __hip_bfloat16* vT    = (__hip_bfloat16*)(ws + 52985856);   // 48x64x784 (+64K slack)
  __hip_bfloat16* wTq   = (__hip_bfloat16*)(ws + 57868288);   // 384x384
  __hip_bfloat16* wTkv  = (__hip_bfloat16*)(ws + 58163200);   // 768x384
  __hip_bfloat16* wTo   = (__hip_bfloat16*)(ws + 58753024);   // 384x384

  dwconv_bn_v4<56,1,1><<<dim3(9408),256,0,stream>>>(x,wdwq,gq,bq,mq,vq,yq);
  dwconv_bn_v4<28,2,0><<<dim3(2352),256,0,stream>>>(x,wdwkv,gkv,bkv,mkv,vkv,ykv);
  transpose_all_kernel<<<dim3(2304),256,0,stream>>>(wpwq, wpwkv, wout, wTq, wTkv, wTo);
  gemm128_kernel<0><<<dim3(3,196),256,0,stream>>>(yq, wTq, qbuf, nullptr, 25088,384,384, nullptr, nullptr);
  gemm128_kernel<1><<<dim3(6,49),256,0,stream>>>(ykv, wTkv, kvbuf, nullptr, 6272,768,384, nullptr, vT);
  attn_kernel<<<dim3(49,48),256,0,stream>>>(qbuf, kvbuf, vT, yq);
  gemm128_kernel<2><<<dim3(3,196),256,0,stream>>>(yq, wTo, nullptr, (float*)d_out, 25088,384,384, bout, nullptr);
}

// Round 13
// 268.159 us; speedup vs baseline: 1.1152x; 1.0620x over previous
//
#include <hip/hip_runtime.h>
#include <hip/hip_bf16.h>
#include <stdint.h>

typedef float  f32x4  __attribute__((ext_vector_type(4)));
typedef __bf16 bf16x8 __attribute__((ext_vector_type(8)));

#define DEV static __device__ __forceinline__

// XOR swizzle for LDS tiles with 128B rows: byte ^= ((row&7)<<4), row = byte>>7
DEV uint32_t swz128(uint32_t b){ return b ^ ((b>>3)&0x70u); }

// async global->LDS, 16B per lane; LDS dest = wave-uniform base + lane*16
DEV void gl_lds16(const void* g, void* l) {
  __builtin_amdgcn_global_load_lds(
      (__attribute__((address_space(1))) void*)(g),
      (__attribute__((address_space(3))) void*)(l), 16, 0, 0);
}

DEV f32x4 mfma16(bf16x8 a, bf16x8 b, f32x4 c) {
  return __builtin_amdgcn_mfma_f32_16x16x32_bf16(a, b, c, 0, 0, 0);
}

DEV uint32_t pkbf(float a, float b) {
  union { __hip_bfloat162 v; uint32_t u; } c;
  c.v.x = __float2bfloat16(a);
  c.v.y = __float2bfloat16(b);
  return c.u;
}

// ------- dwconv 3x3 s1 p1 + BN, q path: 4-wide j-tile, float4 channels ------
// Thread = (b, i, j0..j0+3, c4). Input cols j0-1..j0+4 shared by the 4 outputs:
// 18 x-loads + 9 w-loads per 4 outputs (was 36+36). XCD-chunked (2352%8==0).
__global__ __launch_bounds__(256) void dwconv_bn_q4(
    const float* __restrict__ x, const float* __restrict__ wdw,
    const float* __restrict__ gamma, const float* __restrict__ beta,
    const float* __restrict__ mean, const float* __restrict__ var,
    __hip_bfloat16* __restrict__ y)
{
  constexpr int NWG = 2352;                 // 8*56*14*96 / 256
  const int wg = blockIdx.x;
  const int xcd = wg & 7, o = wg >> 3;
  constexpr int qq = NWG >> 3;              // 294 (rr==0)
  const int swz = xcd*qq + o;
  const int idx = swz*256 + (int)threadIdx.x;
  const int c4 = idx % 96;
  int t = idx / 96;
  const int jq = t % 14; t /= 14;
  const int i = t % 56; const int b = t / 56;
  const int j0 = jq*4;

  const float* xb = x + (size_t)b*(56*56*384) + c4*4;
  const float* wb = wdw + c4*4;
  f32x4 acc[4];
  #pragma unroll
  for (int k=0;k<4;++k) acc[k] = f32x4{0.f,0.f,0.f,0.f};

  #pragma unroll
  for (int di=0; di<3; ++di) {
    const int ii = i + di - 1;
    const bool rok = (unsigned)ii < 56u;
    f32x4 xr[6];
    #pragma unroll
    for (int cj=0; cj<6; ++cj) {
      const int jj = j0 + cj - 1;
      if (rok && (unsigned)jj < 56u)
        xr[cj] = *(const f32x4*)(xb + ((size_t)ii*56 + jj)*384);
      else
        xr[cj] = f32x4{0.f,0.f,0.f,0.f};
    }
    f32x4 w0 = *(const f32x4*)(wb + (di*3+0)*384);
    f32x4 w1 = *(const f32x4*)(wb + (di*3+1)*384);
    f32x4 w2 = *(const f32x4*)(wb + (di*3+2)*384);
    #pragma unroll
    for (int k=0;k<4;++k)
      acc[k] += xr[k]*w0 + xr[k+1]*w1 + xr[k+2]*w2;
  }

  f32x4 g  = *(const f32x4*)(gamma + c4*4);
  f32x4 be = *(const f32x4*)(beta  + c4*4);
  f32x4 mu = *(const f32x4*)(mean  + c4*4);
  f32x4 va = *(const f32x4*)(var   + c4*4);
  f32x4 sc, of;
  #pragma unroll
  for (int k=0;k<4;++k) {
    sc[k] = g[k]*rsqrtf(va[k]+1e-5f);
    of[k] = be[k] - mu[k]*sc[k];
  }
  char* yb = (char*)y + ((size_t)((b*56+i)*56 + j0)*96 + c4)*8;
  #pragma unroll
  for (int oj=0;oj<4;++oj) {
    union { ushort u[4]; uint2 v; } pk;
    #pragma unroll
    for (int k=0;k<4;++k) {
      union { __hip_bfloat16 h; ushort s; } cv;
      cv.h = __float2bfloat16(acc[oj][k]*sc[k] + of[k]);
      pk.u[k] = cv.s;
    }
    *(uint2*)(yb + (size_t)oj*768) = pk.v;
  }
}

// ------- depthwise 3x3 conv + BN, float4-vectorized, XCD-chunked (kv path) ---
template<int HOUT, int STRIDE, int PAD>
__global__ __launch_bounds__(256) void dwconv_bn_v4(
    const float* __restrict__ x, const float* __restrict__ wdw,
    const float* __restrict__ gamma, const float* __restrict__ beta,
    const float* __restrict__ mean, const float* __restrict__ var,
    __hip_bfloat16* __restrict__ y)
{
  constexpr int TOTAL4 = 8*HOUT*HOUT*96;
  constexpr int NWG = (TOTAL4 + 255)/256;
  const int wg = blockIdx.x;
  const int xcd = wg & 7, o = wg >> 3;
  constexpr int qq = NWG >> 3, rr = NWG & 7;
  const int swz = (xcd < rr ? xcd*(qq+1) : rr*(qq+1) + (xcd-rr)*qq) + o;
  const int idx = swz*256 + (int)threadIdx.x;
  if (idx >= TOTAL4) return;
  const int c4 = idx % 96;
  int t = idx / 96;
  const int j = t % HOUT; t /= HOUT;
  const int i = t % HOUT; const int b = t / HOUT;

  const float* xb = x + (size_t)b*(56*56*384) + c4*4;
  f32x4 acc = {0.f,0.f,0.f,0.f};
  #pragma unroll
  for (int di=0; di<3; ++di) {
    const int ii = i*STRIDE + di - PAD;
    if ((unsigned)ii < 56u) {
      #pragma unroll
      for (int dj=0; dj<3; ++dj) {
        const int jj = j*STRIDE + dj - PAD;
        if ((unsigned)jj < 56u) {
          f32x4 xv = *(const f32x4*)(xb + ((size_t)ii*56 + jj)*384);
          f32x4 wv = *(const f32x4*)(wdw + (di*3+dj)*384 + c4*4);
          acc += xv*wv;
        }
      }
    }
  }
  f32x4 g  = *(const f32x4*)(gamma + c4*4);
  f32x4 be = *(const f32x4*)(beta  + c4*4);
  f32x4 mu = *(const f32x4*)(mean  + c4*4);
  f32x4 va = *(const f32x4*)(var   + c4*4);
  union { ushort u[4]; uint2 v; } pk;
  #pragma unroll
  for (int k=0;k<4;++k) {
    float sc = g[k]*rsqrtf(va[k]+1e-5f);
    union { __hip_bfloat16 h; ushort s; } cv;
    cv.h = __float2bfloat16((acc[k]-mu[k])*sc + be[k]);
    pk.u[k] = cv.s;
  }
  *(uint2*)((char*)y + (size_t)idx*8) = pk.v;
}

// ---------------- merged weight transposes: w(K,N) fp32 -> wT(N,K) bf16 ------
__global__ __launch_bounds__(256) void transpose_all_kernel(
    const float* __restrict__ wq, const float* __restrict__ wkv,
    const float* __restrict__ wo,
    __hip_bfloat16* __restrict__ wTq, __hip_bfloat16* __restrict__ wTkv,
    __hip_bfloat16* __restrict__ wTo)
{
  int i = blockIdx.x*256 + threadIdx.x;
  if (i < 147456) {                       // 384x384
    int n = i / 384, k = i - n*384;
    wTq[i] = __float2bfloat16(wq[(size_t)k*384 + n]);
  } else if (i < 147456 + 294912) {       // 768x384 (N=768)
    int idx = i - 147456;
    int n = idx / 384, k = idx - n*384;
    wTkv[idx] = __float2bfloat16(wkv[(size_t)k*768 + n]);
  } else if (i < 147456 + 294912 + 147456) {
    int idx = i - 442368;
    int n = idx / 384, k = idx - n*384;
    wTo[idx] = __float2bfloat16(wo[(size_t)k*384 + n]);
  }
}

// ---------------- 128x128x(K) bf16 GEMM, single-buffered (round-9 proven) ----
// EPI 0: bf16 C. EPI 1: + v-half transposed scatter. EPI 2: bias + f32 C.
template<int EPI>
__global__ __launch_bounds__(256,2) void gemm128_kernel(
    const __hip_bfloat16* __restrict__ A, const __hip_bfloat16* __restrict__ Bt,
    __hip_bfloat16* __restrict__ C, float* __restrict__ Cf, int M, int N, int K,
    const float* __restrict__ bias, __hip_bfloat16* __restrict__ vT)
{
  __shared__ __align__(1024) char As[128*64*2];
  __shared__ __align__(1024) char Bs[128*64*2];
  const int t = threadIdx.x;
  const int lane = t & 63;
  const int wave = t >> 6;
  const int wr = wave >> 1, wc = wave & 1;
  const int m0 = blockIdx.y*128, n0 = blockIdx.x*128;
  const int ldab = K*2;

  const char* aS[4]; const char* bS[4];
  #pragma unroll
  for (int j=0;j<4;++j) {
    uint32_t d = (uint32_t)(j*256 + t)*16u;
    uint32_t l = swz128(d);
    uint32_t r = l >> 7, cb = l & 127u;
    aS[j] = (const char*)A  + (size_t)(m0+(int)r)*ldab + cb;
    bS[j] = (const char*)Bt + (size_t)(n0+(int)r)*ldab + cb;
  }
  f32x4 acc[4][4];
  #pragma unroll
  for (int m=0;m<4;++m)
    #pragma unroll
    for (int n=0;n<4;++n)
      acc[m][n] = f32x4{0.f,0.f,0.f,0.f};

  const uint32_t kbOff = (uint32_t)((lane>>4)*16);
  const uint32_t arow = (uint32_t)(wr*64 + (lane&15));
  const uint32_t brow = (uint32_t)(wc*64 + (lane&15));

  const int nk = K >> 6;
  for (int kt=0; kt<nk; ++kt) {
    #pragma unroll
    for (int j=0;j<4;++j) {
      uint32_t d = (uint32_t)(j*256+t)*16u;
      gl_lds16(aS[j] + (size_t)kt*128, As + d);
      gl_lds16(bS[j] + (size_t)kt*128, Bs + d);
    }
    __syncthreads();
    #pragma unroll
    for (int ks=0;ks<2;++ks) {
      bf16x8 af[4], bf[4];
      #pragma unroll
      for (int m=0;m<4;++m)
        af[m] = *(const bf16x8*)(As + swz128((arow + m*16)*128 + ks*64 + kbOff));
      #pragma unroll
      for (int n=0;n<4;++n)
        bf[n] = *(const bf16x8*)(Bs + swz128((brow + n*16)*128 + ks*64 + kbOff));
      #pragma unroll
      for (int m=0;m<4;++m)
        #pragma unroll
        for (int n=0;n<4;++n)
          acc[m][n] = mfma16(af[m], bf[n], acc[m][n]);
    }
    __syncthreads();
  }
  #pragma unroll
  for (int m=0;m<4;++m) {
    #pragma unroll
    for (int n=0;n<4;++n) {
      #pragma unroll
      for (int i=0;i<4;++i) {
        int row = m0 + wr*64 + m*16 + (lane>>4)*4 + i;
        int col = n0 + wc*64 + n*16 + (lane&15);
        float v = acc[m][n][i];
        if (EPI==2) {
          Cf[(size_t)row*N + col] = v + bias[col];
        } else {
          C[(size_t)row*N + col] = __float2bfloat16(v);
          if (EPI==1 && col >= 384) {
            int bb = row / 784;
            int p  = row - bb*784;
            int cc = col - 384;
            int hh = cc >> 6, dd2 = cc & 63;
            vT[(size_t)((bb*6+hh)*64+dd2)*784 + p] = __float2bfloat16(v);
          }
        }
      }
    }
  }
}

// ---------------- flash attention v3.1: zero-hoist + no tile-13 prefetch ----
__global__ __launch_bounds__(256,4) void attn_kernel(
    const __hip_bfloat16* __restrict__ qb, const __hip_bfloat16* __restrict__ kvb,
    const __hip_bfloat16* __restrict__ vTb, __hip_bfloat16* __restrict__ ob)
{
  __shared__ __align__(1024) char Ks[2*8192];   // [buf][64 kv x 64 d] swz128
  __shared__ __align__(1024) char Vs[2*8192];   // [buf][64 d x 64 kv] swz128
  __shared__ __align__(1024) char Ps[4*2048];   // per-wave [16 q x 64 kv] swz128
  const int t = threadIdx.x, lane = t&63, w = t>>6;
  const int bh = blockIdx.y;
  const int b = bh / 6, h = bh - b*6;
  const int qp0 = blockIdx.x * 64;

  const float K1 = 0.18033688011112042f;   // 0.125 * log2(e)
  const float C2 = 5.770780163555851f;     // 4.0  * log2(e)

  const char* qrow = (const char*)qb
      + ((size_t)(b*3136 + qp0 + w*16 + (lane&15))*384 + h*64)*2 + (lane>>4)*16;
  bf16x8 aq[2];
  aq[0] = *(const bf16x8*)(qrow);
  aq[1] = *(const bf16x8*)(qrow + 64);

  const char* kbase = (const char*)kvb + ((size_t)(b*784)*768 + h*64)*2;  // row 1536B
  const char* vbase = (const char*)vTb + (size_t)((b*6+h)*64)*1568;       // row 1568B

  const uint32_t d0 = (uint32_t)t*16u, d1 = (uint32_t)(256+t)*16u;
  const uint32_t l0 = swz128(d0), l1 = swz128(d1);
  const int      kr0 = (int)(l0>>7), kr1 = (int)(l1>>7);
  const uint32_t c0 = l0&127u, c1 = l1&127u;

  #define STAGE(buf, kv0) do {                                               \
    int a0 = (kv0)+kr0; if (a0>783) a0=783;                                  \
    int a1 = (kv0)+kr1; if (a1>783) a1=783;                                  \
    gl_lds16(kbase + (size_t)a0*1536 + c0, Ks + (buf)*8192 + d0);            \
    gl_lds16(kbase + (size_t)a1*1536 + c1, Ks + (buf)*8192 + d1);            \
    gl_lds16(vbase + (size_t)kr0*1568 + (size_t)(kv0)*2 + c0, Vs + (buf)*8192 + d0); \
    gl_lds16(vbase + (size_t)kr1*1568 + (size_t)(kv0)*2 + c1, Vs + (buf)*8192 + d1); \
  } while(0)

  STAGE(0, 0);
  asm volatile("s_waitcnt vmcnt(0)" ::: "memory");
  __syncthreads();

  float l_part = 0.f;
  f32x4 o[4];
  #pragma unroll
  for (int nf=0;nf<4;++nf) o[nf] = f32x4{0.f,0.f,0.f,0.f};
  f32x4 z = {0.f,0.f,0.f,0.f};
  asm volatile("" : "+v"(z));   // pin zero C-operand in regs (kills per-iter init)

  char* Pb = Ps + w*2048;
  const uint32_t fragOff = (uint32_t)((lane>>4)*16);
  const uint32_t pwBase = (uint32_t)(lane&15)*128 + (uint32_t)((lane>>4)*4)*2;

  for (int kt=0; kt<13; ++kt) {
    const int cur = kt & 1;
    if (kt < 12) STAGE(cur^1, (kt+1)*64);
    const char* Kb = Ks + cur*8192;
    const char* Vb = Vs + cur*8192;

    // S^T = (K Q^T): s[nf][i] = S[kv=nf*16+(lane>>4)*4+i][q=lane&15]
    f32x4 s[4];
    #pragma unroll
    for (int nf=0;nf<4;++nf) {
      bf16x8 kf0 = *(const bf16x8*)(Kb + swz128((uint32_t)(nf*16+(lane&15))*128 + fragOff));
      s[nf] = mfma16(kf0, aq[0], z);
      bf16x8 kf1 = *(const bf16x8*)(Kb + swz128((uint32_t)(nf*16+(lane&15))*128 + 64 + fragOff));
      s[nf] = mfma16(kf1, aq[1], s[nf]);
    }

    // P = 2^(S*K1 - C2); tail tile: only frag nf=0 valid (kv 768..783)
    #pragma unroll
    for (int nf=0;nf<4;++nf) {
      uint64_t pk;
      if (kt == 12 && nf > 0) {
        pk = 0ull;
      } else {
        float p0 = exp2f(fmaf(s[nf][0], K1, -C2));
        float p1 = exp2f(fmaf(s[nf][1], K1, -C2));
        float p2 = exp2f(fmaf(s[nf][2], K1, -C2));
        float p3 = exp2f(fmaf(s[nf][3], K1, -C2));
        l_part += (p0+p1) + (p2+p3);
        pk = (uint64_t)pkbf(p2,p3) << 32 | pkbf(p0,p1);
      }
      *(uint64_t*)(Pb + swz128(pwBase + nf*32)) = pk;
    }

    // O += P V
    #pragma unroll
    for (int ks=0;ks<2;++ks) {
      bf16x8 pa = *(const bf16x8*)(Pb + swz128((uint32_t)(lane&15)*128 + ks*64 + fragOff));
      #pragma unroll
      for (int nf=0;nf<4;++nf) {
        bf16x8 vf = *(const bf16x8*)(Vb + swz128((uint32_t)(nf*16+(lane&15))*128 + ks*64 + fragOff));
        o[nf] = mfma16(pa, vf, o[nf]);
      }
    }

    asm volatile("s_waitcnt vmcnt(0)" ::: "memory");
    __syncthreads();
  }
  #undef STAGE

  l_part += __shfl_xor(l_part, 16);
  l_part += __shfl_xor(l_part, 32);

  char* obase = (char*)ob + ((size_t)(b*3136 + qp0 + w*16 + (lane>>4)*4)*384 + h*64 + (lane&15))*2;
  #pragma unroll
  for (int i=0;i<4;++i) {
    float li = __shfl(l_part, (lane>>4)*4 + i);
    float inv = 1.0f / li;
    #pragma unroll
    for (int nf=0;nf<4;++nf)
      *(__hip_bfloat16*)(obase + (size_t)i*768 + nf*32) = __float2bfloat16(o[nf][i]*inv);
  }
}

// ---------------- launch --------------------------------------------------
extern "C" void kernel_launch(void* const* d_in, const int* in_sizes, int n_in,
                              void* d_out, int out_size, void* d_ws, size_t ws_size,
                              hipStream_t stream)
{
  const float* x      = (const float*)d_in[0];
  const float* wdwq   = (const float*)d_in[1];
  const float* gq     = (const float*)d_in[2];
  const float* bq     = (const float*)d_in[3];
  const float* mq     = (const float*)d_in[4];
  const float* vq     = (const float*)d_in[5];
  const float* wpwq   = (const float*)d_in[6];
  const float* wdwkv  = (const float*)d_in[7];
  const float* gkv    = (const float*)d_in[8];
  const float* bkv    = (const float*)d_in[9];
  const float* mkv    = (const float*)d_in[10];
  const float* vkv    = (const float*)d_in[11];
  const float* wpwkv  = (const float*)d_in[12];
  const float* wout   = (const float*)d_in[13];
  const float* bout   = (const float*)d_in[14];

  char* ws = (char*)d_ws;
  __hip_bfloat16* yq    = (__hip_bfloat16*)(ws + 0);          // 25088x384 (reused as o)
  __hip_bfloat16* qbuf  = (__hip_bfloat16*)(ws + 19267584);   // 25088x384
  __hip_bfloat16* ykv   = (__hip_bfloat16*)(ws + 38535168);   // 6272x384
  __hip_bfloat16* kvbuf = (__hip_bfloat16*)(ws + 43352064);   // 6272x768
  __hip_bfloat16* vT    = (__hip_bfloat16*)(ws + 52985856);   // 48x64x784 (+64K slack)
  __hip_bfloat16* wTq   = (__hip_bfloat16*)(ws + 57868288);   // 384x384
  __hip_bfloat16* wTkv  = (__hip_bfloat16*)(ws + 58163200);   // 768x384
  __hip_bfloat16* wTo   = (__hip_bfloat16*)(ws + 58753024);   // 384x384

  dwconv_bn_q4<<<dim3(2352),256,0,stream>>>(x,wdwq,gq,bq,mq,vq,yq);
  dwconv_bn_v4<28,2,0><<<dim3(2352),256,0,stream>>>(x,wdwkv,gkv,bkv,mkv,vkv,ykv);
  transpose_all_kernel<<<dim3(2304),256,0,stream>>>(wpwq, wpwkv, wout, wTq, wTkv, wTo);
  gemm128_kernel<0><<<dim3(3,196),256,0,stream>>>(yq, wTq, qbuf, nullptr, 25088,384,384, nullptr, nullptr);
  gemm128_kernel<1><<<dim3(6,49),256,0,stream>>>(ykv, wTkv, kvbuf, nullptr, 6272,768,384, nullptr, vT);
  attn_kernel<<<dim3(49,48),256,0,stream>>>(qbuf, kvbuf, vT, yq);
  gemm128_kernel<2><<<dim3(3,196),256,0,stream>>>(yq, wTo, nullptr, (float*)d_out, 25088,384,384, bout, nullptr);
}